// Round 5
// baseline (550.089 us; speedup 1.0000x reference)
//
#include <hip/hip_runtime.h>
#include <hip/hip_bf16.h>
#include <hip/hip_fp16.h>

typedef float f32x4 __attribute__((ext_vector_type(4)));
typedef float f32x2 __attribute__((ext_vector_type(2)));
typedef __bf16 bf16x8 __attribute__((ext_vector_type(8)));
typedef short s16x8 __attribute__((ext_vector_type(8)));
typedef unsigned short u16;
typedef unsigned short ushort4v __attribute__((ext_vector_type(4)));

#define HWSZ 16384
#define NPIX 131072

// ws byte offsets (total ~43.1 MB)
#define XT_OFF    0u          // float[NPIX*64]  x transposed to NHWC
#define OFFS_OFF  33554432u   // float[NPIX*18]  offset-conv output, [pix][18]
#define WB_OFF    42991616u   // u16[64*576]     deform_w as bf16, [o][k2*64+c]
#define OFFR_OFF  43065344u   // float[576*18]   offset_w reordered [k2*64+c][18]
#define STATS_OFF 43106816u   // float[256]: sums[64], sumsq[64], scale[64], shift[64]

__device__ inline float dpp_add_x1(float v) {   // v + shfl_xor(v,1) via quad_perm [1,0,3,2]
  int x = __builtin_amdgcn_update_dpp(0, __builtin_bit_cast(int, v), 0xB1, 0xF, 0xF, true);
  return v + __builtin_bit_cast(float, x);
}
__device__ inline float dpp_add_x2(float v) {   // v + shfl_xor(v,2) via quad_perm [2,3,0,1]
  int x = __builtin_amdgcn_update_dpp(0, __builtin_bit_cast(int, v), 0x4E, 0xF, 0xF, true);
  return v + __builtin_bit_cast(float, x);
}

// ---- prep: reorder/convert weights, zero BN stats ----
__global__ void kprep(const float* __restrict__ dw, const float* __restrict__ ow,
                      u16* __restrict__ Wb, float* __restrict__ offr,
                      float* __restrict__ stats) {
  int t = blockIdx.x * 256 + threadIdx.x;
  if (t < 256) stats[t] = 0.f;
  if (t < 36864) {                      // deform_w (64,64,3,3) -> Wb[o][k2*64+c] bf16
    int o = t / 576, r = t % 576;
    int c = r / 9, k2 = r % 9;
    __hip_bfloat16 h = __float2bfloat16(dw[t]);
    Wb[o * 576 + k2 * 64 + c] = __builtin_bit_cast(u16, h);
  } else if (t < 47232) {               // offset_w (18,64,3,3) -> offr[k2*64+c][18]
    int t2 = t - 36864;
    int oc = t2 / 576, r = t2 % 576;
    int c = r / 9, k2 = r % 9;
    offr[(k2 * 64 + c) * 18 + oc] = ow[t2];
  }
}

// ---- NCHW -> NHWC transpose of x ----
__global__ void ktrans(const float* __restrict__ x, float* __restrict__ xt) {
  __shared__ float tile[64][65];
  int blk = blockIdx.x;
  int b = blk >> 8, hwT = (blk & 255) * 64;
  int tx = threadIdx.x & 63, ty = threadIdx.x >> 6;
  const float* xp = x + (size_t)b * 64 * HWSZ;
#pragma unroll
  for (int r = 0; r < 16; ++r) {
    int c = r * 4 + ty;
    tile[c][tx] = xp[c * HWSZ + hwT + tx];
  }
  __syncthreads();
  float* xo = xt + ((size_t)b * HWSZ + hwT) * 64;
#pragma unroll
  for (int r = 0; r < 16; ++r) {
    int hwl = r * 4 + ty;
    xo[hwl * 64 + tx] = tile[tx][hwl];
  }
}

// ---- offset conv: 3x3, 64->18 ch, fp32, thread per pixel ----
__global__ void koffc(const float* __restrict__ xt, const float* __restrict__ offr,
                      const float* __restrict__ offb, float* __restrict__ offs) {
  int pix = blockIdx.x * 256 + threadIdx.x;
  int b = pix >> 14, hw = pix & 16383;
  int h = hw >> 7, w = hw & 127;
  float acc[18];
#pragma unroll
  for (int oc = 0; oc < 18; ++oc) acc[oc] = offb[oc];
#pragma unroll
  for (int k2 = 0; k2 < 9; ++k2) {
    int y = h - 1 + k2 / 3, x = w - 1 + k2 % 3;
    if ((unsigned)y < 128u && (unsigned)x < 128u) {
      const float* px = xt + (((b << 7) + y << 7) + x) * 64;
      const float* wr = offr + k2 * 64 * 18;
      for (int c = 0; c < 64; c += 4) {
        f32x4 xv = *(const f32x4*)(px + c);
#pragma unroll
        for (int j = 0; j < 4; ++j)
#pragma unroll
          for (int oc = 0; oc < 18; ++oc)
            acc[oc] = fmaf(wr[(c + j) * 18 + oc], xv[j], acc[oc]);
      }
    }
  }
  float* op = offs + (size_t)pix * 18;
#pragma unroll
  for (int oc = 0; oc < 18; ++oc) op[oc] = acc[oc];
}

// ---- deformable conv: asm-batched gathers (forced ILP) + DPP reduce + MFMA ----
// block: 256 thr = 4 waves; tile = 64 o x 32 pixels; K = 576 (k2*64+c)
// LDS: S 36864 + OFF 2304 = 39168 B -> 4 blocks/CU
// XCD remap: batch = bid&7 pins each 4MB image to one XCD's L2.
__global__ __launch_bounds__(256, 4) void kdeform(
    const float* __restrict__ xt, const float* __restrict__ offs,
    const u16* __restrict__ Wb, const float* __restrict__ db,
    float* __restrict__ y, float* __restrict__ stats) {
  __shared__ u16 S[32 * 576];          // XOR-swizzled: u16idx ^= (row&7)<<3
  __shared__ float OFF[576];           // this block's 32 pixels x 18 offsets
  int tid = threadIdx.x;
  int lane = tid & 63, wid = tid >> 6;
  int bid = blockIdx.x;
  int batch = bid & 7, tile = bid >> 3;
  int base = (batch << 14) + tile * 32;
  int b = batch;

  // stage this block's offsets into LDS (coalesced, once)
  if (tid < 144)
    ((f32x4*)OFF)[tid] = *(const f32x4*)(offs + (size_t)base * 18 + tid * 4);
  __syncthreads();

  // sampling lane decomposition: corner = lane&3 (00,01,10,11 = y0x0,y0x1,y1x0,y1x1)
  int corner = lane & 3, c4 = lane >> 2;
  int gxsel = lane & 1, gysel = (lane >> 1) & 1;
  int lanebyte = c4 << 4;
  int shamt = gxsel << 4;              // 0 or 16: which half of packed weight

  // meta lanes: lane t<9 computes tap t
  int t = lane;
  int ky = t / 3, kx = t % 3;
  int tt = (t < 9) ? t : 0;

  int p0 = wid * 8;
  // per-pixel offsets for this wave, registers (lanes 0..8 meaningful)
  f32x2 dd[8];
#pragma unroll
  for (int i = 0; i < 8; ++i)
    dd[i] = *(const f32x2*)&OFF[(p0 + i) * 18 + 2 * tt];

  auto meta = [&](int pix, f32x2 dc, int& MO, int& WA, int& WB2) {
    int hw = pix & 16383;
    int h = hw >> 7, w = hw & 127;
    float sy = (float)(h - 1 + ky) + dc.x;
    float sx = (float)(w - 1 + kx) + dc.y;
    float fy = floorf(sy), fx = floorf(sx);
    int y0 = (int)fy, x0 = (int)fx;
    float wy1 = sy - fy, wx1 = sx - fx;
    float ay0 = ((unsigned)y0 < 128u) ? 1.f - wy1 : 0.f;
    float ay1 = ((unsigned)(y0 + 1) < 128u) ? wy1 : 0.f;
    float ax0 = ((unsigned)x0 < 128u) ? 1.f - wx1 : 0.f;
    float ax1 = ((unsigned)(x0 + 1) < 128u) ? wx1 : 0.f;
    int y0c = min(max(y0, 0), 127), x0c = min(max(x0, 0), 127);
    int dys = min(max(y0 + 1, 0), 127) - y0c;
    int dxs = min(max(x0 + 1, 0), 127) - x0c;
    MO = ((b << 14) + y0c * 128 + x0c) | (dxs << 24) | (dys << 25);
    WA = __builtin_bit_cast(int, __floats2half2_rn(ay0 * ax0, ay0 * ax1));
    WB2 = __builtin_bit_cast(int, __floats2half2_rn(ay1 * ax0, ay1 * ax1));
  };

  auto sample_one = [&](int i) {
    int p = p0 + i;
    int pix = base + p;
    int MO, WA, WB2;
    meta(pix, dd[i], MO, WA, WB2);
    int smo[9], swA[9], swB[9];
#pragma unroll
    for (int k = 0; k < 9; ++k) {
      smo[k] = __builtin_amdgcn_readlane(MO, k);
      swA[k] = __builtin_amdgcn_readlane(WA, k);
      swB[k] = __builtin_amdgcn_readlane(WB2, k);
    }
    // batch-issue all 9 dwordx4 gathers via asm (compiler cannot serialize)
    f32x4 vv[9];
#pragma unroll
    for (int k = 0; k < 9; ++k) {
      int mk = smo[k];
      int sdx = (mk >> 24) & 1;
      int sdy = ((mk >> 25) & 1) << 7;
      int po = (mk & 0xFFFFFF) + (gxsel ? sdx : 0) + (gysel ? sdy : 0);
      const char* ap = (const char*)xt + ((size_t)(unsigned)po << 8) + lanebyte;
      asm volatile("global_load_dwordx4 %0, %1, off" : "=v"(vv[k]) : "v"(ap));
    }
    asm volatile("s_waitcnt vmcnt(0)");
    __builtin_amdgcn_sched_barrier(0);
    // weighted cross-corner reduce (DPP within quads), group-leader writes LDS
#pragma unroll
    for (int k = 0; k < 9; ++k) {
      int hsel = gysel ? swB[k] : swA[k];
      __half hh = __builtin_bit_cast(__half, (u16)(hsel >> shamt));
      float w = __half2float(hh);
      float r0 = vv[k][0] * w, r1 = vv[k][1] * w, r2 = vv[k][2] * w, r3 = vv[k][3] * w;
      r0 = dpp_add_x2(dpp_add_x1(r0));
      r1 = dpp_add_x2(dpp_add_x1(r1));
      r2 = dpp_add_x2(dpp_add_x1(r2));
      r3 = dpp_add_x2(dpp_add_x1(r3));
      if (corner == 0) {
        ushort4v pk;
        pk.x = __builtin_bit_cast(u16, __float2bfloat16(r0));
        pk.y = __builtin_bit_cast(u16, __float2bfloat16(r1));
        pk.z = __builtin_bit_cast(u16, __float2bfloat16(r2));
        pk.w = __builtin_bit_cast(u16, __float2bfloat16(r3));
        int idx = (p * 576 + k * 64 + (c4 << 2)) ^ ((p & 7) << 3);
        *(ushort4v*)&S[idx] = pk;
      }
    }
  };
#pragma unroll
  for (int i = 0; i < 8; ++i) sample_one(i);

  // A fragments via asm loads (kept out of the sampling vmcnt window)
  s16x8 afr[18];
  const u16* wrow = Wb + (wid * 16 + (lane & 15)) * 576 + (lane >> 4) * 8;
#pragma unroll
  for (int kc = 0; kc < 18; ++kc)
    asm volatile("global_load_dwordx4 %0, %1, off" : "=v"(afr[kc]) : "v"(wrow + kc * 32));

  __syncthreads();
  asm volatile("s_waitcnt vmcnt(0)");
  __builtin_amdgcn_sched_barrier(0);

  f32x4 zero = {0.f, 0.f, 0.f, 0.f};
  f32x4 acc[2] = {zero, zero};
#pragma unroll
  for (int kc = 0; kc < 18; ++kc) {
#pragma unroll
    for (int nf = 0; nf < 2; ++nf) {
      int row = nf * 16 + (lane & 15);
      int idx = (row * 576 + kc * 32 + (lane >> 4) * 8) ^ ((row & 7) << 3);
      bf16x8 bfr = __builtin_bit_cast(bf16x8, *(const s16x8*)&S[idx]);
      acc[nf] = __builtin_amdgcn_mfma_f32_16x16x32_bf16(
          __builtin_bit_cast(bf16x8, afr[kc]), bfr, acc[nf], 0, 0, 0);
    }
  }

  // epilogue: write y (NCHW) + per-channel partial sums
  int obase = wid * 16 + (lane >> 4) * 4;
  float s1[4] = {0, 0, 0, 0}, s2[4] = {0, 0, 0, 0};
#pragma unroll
  for (int nf = 0; nf < 2; ++nf) {
    int pix = base + nf * 16 + (lane & 15);
    int hw = pix & 16383;
    float* yp = y + (size_t)b * (64 * HWSZ) + hw;
#pragma unroll
    for (int r = 0; r < 4; ++r) {
      int o = obase + r;
      float v = acc[nf][r] + db[o];
      yp[(size_t)o * HWSZ] = v;
      s1[r] += v;
      s2[r] += v * v;
    }
  }
#pragma unroll
  for (int m = 1; m < 16; m <<= 1) {
#pragma unroll
    for (int r = 0; r < 4; ++r) {
      s1[r] += __shfl_xor(s1[r], m, 64);
      s2[r] += __shfl_xor(s2[r], m, 64);
    }
  }
  if ((lane & 15) == 0) {
#pragma unroll
    for (int r = 0; r < 4; ++r) {
      atomicAdd(&stats[obase + r], s1[r]);
      atomicAdd(&stats[64 + obase + r], s2[r]);
    }
  }
}

// ---- BN finalize: scale/shift per channel ----
__global__ void kbn(const float* __restrict__ gamma, const float* __restrict__ beta,
                    float* __restrict__ stats) {
  int o = threadIdx.x;
  if (o < 64) {
    float m = stats[o] * (1.f / 131072.f);
    float v = stats[64 + o] * (1.f / 131072.f) - m * m;
    float sc = gamma[o] * rsqrtf(v + 1e-5f);
    stats[128 + o] = sc;
    stats[192 + o] = beta[o] - m * sc;
  }
}

// ---- in-place scale/shift + PReLU on y (= d_out) ----
__global__ void kfinal(float* __restrict__ y, const float* __restrict__ stats,
                       const float* __restrict__ pa) {
  float a = pa[0];
  int total = NPIX * 64 / 4;
  for (int i = blockIdx.x * blockDim.x + threadIdx.x; i < total;
       i += gridDim.x * blockDim.x) {
    int o = (i >> 12) & 63;
    f32x4 v = ((const f32x4*)y)[i];
    float sc = stats[128 + o], sh = stats[192 + o];
#pragma unroll
    for (int j = 0; j < 4; ++j) {
      float t = fmaf(v[j], sc, sh);
      v[j] = t >= 0.f ? t : a * t;
    }
    ((f32x4*)y)[i] = v;
  }
}

extern "C" void kernel_launch(void* const* d_in, const int* in_sizes, int n_in,
                              void* d_out, int out_size, void* d_ws, size_t ws_size,
                              hipStream_t stream) {
  const float* x  = (const float*)d_in[0];
  const float* ow = (const float*)d_in[1];
  const float* ob = (const float*)d_in[2];
  const float* dw = (const float*)d_in[3];
  const float* db = (const float*)d_in[4];
  const float* gm = (const float*)d_in[5];
  const float* bt = (const float*)d_in[6];
  const float* pa = (const float*)d_in[7];
  char* ws = (char*)d_ws;
  float* xt    = (float*)(ws + XT_OFF);
  float* offs  = (float*)(ws + OFFS_OFF);
  u16*   Wb    = (u16*)(ws + WB_OFF);
  float* offr  = (float*)(ws + OFFR_OFF);
  float* stats = (float*)(ws + STATS_OFF);
  float* y = (float*)d_out;   // d_out doubles as the pre-BN activation buffer

  kprep<<<185, 256, 0, stream>>>(dw, ow, Wb, offr, stats);
  ktrans<<<2048, 256, 0, stream>>>(x, xt);
  koffc<<<512, 256, 0, stream>>>(xt, offr, ob, offs);
  kdeform<<<4096, 256, 0, stream>>>(xt, offs, Wb, db, y, stats);
  kbn<<<1, 64, 0, stream>>>(gm, bt, stats);
  kfinal<<<2048, 256, 0, stream>>>(y, stats, pa);
}

// Round 6
// 312.296 us; speedup vs baseline: 1.7614x; 1.7614x over previous
//
#include <hip/hip_runtime.h>
#include <hip/hip_bf16.h>
#include <hip/hip_fp16.h>

typedef float f32x4 __attribute__((ext_vector_type(4)));
typedef float f32x2 __attribute__((ext_vector_type(2)));
typedef __bf16 bf16x8 __attribute__((ext_vector_type(8)));
typedef short s16x8 __attribute__((ext_vector_type(8)));
typedef unsigned short u16;
typedef unsigned short ushort4v __attribute__((ext_vector_type(4)));

#define HWSZ 16384
#define NPIX 131072

// ws byte offsets (total ~43.1 MB)
#define XT_OFF    0u          // float[NPIX*64]  x transposed to NHWC
#define OFFS_OFF  33554432u   // float[NPIX*18]  offset-conv output, [pix][18]
#define WB_OFF    42991616u   // u16[64*576]     deform_w as bf16, [o][k2*64+c]
#define OFFR_OFF  43065344u   // float[576*18]   offset_w reordered [k2*64+c][18]
#define STATS_OFF 43106816u   // float[256]: (unused)[128], scale[64], shift[64]

__device__ inline float dpp_add_x1(float v) {   // v + shfl_xor(v,1) via quad_perm [1,0,3,2]
  int x = __builtin_amdgcn_update_dpp(0, __builtin_bit_cast(int, v), 0xB1, 0xF, 0xF, true);
  return v + __builtin_bit_cast(float, x);
}
__device__ inline float dpp_add_x2(float v) {   // v + shfl_xor(v,2) via quad_perm [2,3,0,1]
  int x = __builtin_amdgcn_update_dpp(0, __builtin_bit_cast(int, v), 0x4E, 0xF, 0xF, true);
  return v + __builtin_bit_cast(float, x);
}

// ---- prep: reorder/convert weights ----
__global__ void kprep(const float* __restrict__ dw, const float* __restrict__ ow,
                      u16* __restrict__ Wb, float* __restrict__ offr) {
  int t = blockIdx.x * 256 + threadIdx.x;
  if (t < 36864) {                      // deform_w (64,64,3,3) -> Wb[o][k2*64+c] bf16
    int o = t / 576, r = t % 576;
    int c = r / 9, k2 = r % 9;
    __hip_bfloat16 h = __float2bfloat16(dw[t]);
    Wb[o * 576 + k2 * 64 + c] = __builtin_bit_cast(u16, h);
  } else if (t < 47232) {               // offset_w (18,64,3,3) -> offr[k2*64+c][18]
    int t2 = t - 36864;
    int oc = t2 / 576, r = t2 % 576;
    int c = r / 9, k2 = r % 9;
    offr[(k2 * 64 + c) * 18 + oc] = ow[t2];
  }
}

// ---- NCHW -> NHWC transpose of x ----
__global__ void ktrans(const float* __restrict__ x, float* __restrict__ xt) {
  __shared__ float tile[64][65];
  int blk = blockIdx.x;
  int b = blk >> 8, hwT = (blk & 255) * 64;
  int tx = threadIdx.x & 63, ty = threadIdx.x >> 6;
  const float* xp = x + (size_t)b * 64 * HWSZ;
#pragma unroll
  for (int r = 0; r < 16; ++r) {
    int c = r * 4 + ty;
    tile[c][tx] = xp[c * HWSZ + hwT + tx];
  }
  __syncthreads();
  float* xo = xt + ((size_t)b * HWSZ + hwT) * 64;
#pragma unroll
  for (int r = 0; r < 16; ++r) {
    int hwl = r * 4 + ty;
    xo[hwl * 64 + tx] = tile[tx][hwl];
  }
}

// ---- offset conv: 3x3, 64->18 ch, fp32, thread per pixel ----
__global__ void koffc(const float* __restrict__ xt, const float* __restrict__ offr,
                      const float* __restrict__ offb, float* __restrict__ offs) {
  int pix = blockIdx.x * 256 + threadIdx.x;
  int b = pix >> 14, hw = pix & 16383;
  int h = hw >> 7, w = hw & 127;
  float acc[18];
#pragma unroll
  for (int oc = 0; oc < 18; ++oc) acc[oc] = offb[oc];
#pragma unroll
  for (int k2 = 0; k2 < 9; ++k2) {
    int y = h - 1 + k2 / 3, x = w - 1 + k2 % 3;
    if ((unsigned)y < 128u && (unsigned)x < 128u) {
      const float* px = xt + (((b << 7) + y << 7) + x) * 64;
      const float* wr = offr + k2 * 64 * 18;
      for (int c = 0; c < 64; c += 4) {
        f32x4 xv = *(const f32x4*)(px + c);
#pragma unroll
        for (int j = 0; j < 4; ++j)
#pragma unroll
          for (int oc = 0; oc < 18; ++oc)
            acc[oc] = fmaf(wr[(c + j) * 18 + oc], xv[j], acc[oc]);
      }
    }
  }
  float* op = offs + (size_t)pix * 18;
#pragma unroll
  for (int oc = 0; oc < 18; ++oc) op[oc] = acc[oc];
}

// ---- deformable conv: asm-batched gathers + DPP reduce + MFMA (NO atomics) ----
// block: 256 thr = 4 waves; tile = 64 o x 32 pixels; K = 576 (k2*64+c)
// LDS: S 36864 + OFF 2304 = 39168 B -> 4 blocks/CU
__global__ __launch_bounds__(256, 4) void kdeform(
    const float* __restrict__ xt, const float* __restrict__ offs,
    const u16* __restrict__ Wb, const float* __restrict__ db,
    float* __restrict__ y) {
  __shared__ u16 S[32 * 576];          // XOR-swizzled: u16idx ^= (row&7)<<3
  __shared__ float OFF[576];           // this block's 32 pixels x 18 offsets
  int tid = threadIdx.x;
  int lane = tid & 63, wid = tid >> 6;
  int bid = blockIdx.x;
  int batch = bid & 7, tile = bid >> 3;
  int base = (batch << 14) + tile * 32;
  int b = batch;

  // stage this block's offsets into LDS (coalesced, once)
  if (tid < 144)
    ((f32x4*)OFF)[tid] = *(const f32x4*)(offs + (size_t)base * 18 + tid * 4);
  __syncthreads();

  // sampling lane decomposition: corner = lane&3 (00,01,10,11 = y0x0,y0x1,y1x0,y1x1)
  int corner = lane & 3, c4 = lane >> 2;
  int gxsel = lane & 1, gysel = (lane >> 1) & 1;
  int lanebyte = c4 << 4;
  int shamt = gxsel << 4;              // 0 or 16: which half of packed weight

  // meta lanes: lane t<9 computes tap t
  int t = lane;
  int ky = t / 3, kx = t % 3;
  int tt = (t < 9) ? t : 0;

  int p0 = wid * 8;
  f32x2 dd[8];
#pragma unroll
  for (int i = 0; i < 8; ++i)
    dd[i] = *(const f32x2*)&OFF[(p0 + i) * 18 + 2 * tt];

  auto meta = [&](int pix, f32x2 dc, int& MO, int& WA, int& WB2) {
    int hw = pix & 16383;
    int h = hw >> 7, w = hw & 127;
    float sy = (float)(h - 1 + ky) + dc.x;
    float sx = (float)(w - 1 + kx) + dc.y;
    float fy = floorf(sy), fx = floorf(sx);
    int y0 = (int)fy, x0 = (int)fx;
    float wy1 = sy - fy, wx1 = sx - fx;
    float ay0 = ((unsigned)y0 < 128u) ? 1.f - wy1 : 0.f;
    float ay1 = ((unsigned)(y0 + 1) < 128u) ? wy1 : 0.f;
    float ax0 = ((unsigned)x0 < 128u) ? 1.f - wx1 : 0.f;
    float ax1 = ((unsigned)(x0 + 1) < 128u) ? wx1 : 0.f;
    int y0c = min(max(y0, 0), 127), x0c = min(max(x0, 0), 127);
    int dys = min(max(y0 + 1, 0), 127) - y0c;
    int dxs = min(max(x0 + 1, 0), 127) - x0c;
    MO = ((b << 14) + y0c * 128 + x0c) | (dxs << 24) | (dys << 25);
    WA = __builtin_bit_cast(int, __floats2half2_rn(ay0 * ax0, ay0 * ax1));
    WB2 = __builtin_bit_cast(int, __floats2half2_rn(ay1 * ax0, ay1 * ax1));
  };

  auto sample_one = [&](int i) {
    int p = p0 + i;
    int pix = base + p;
    int MO, WA, WB2;
    meta(pix, dd[i], MO, WA, WB2);
    int smo[9], swA[9], swB[9];
#pragma unroll
    for (int k = 0; k < 9; ++k) {
      smo[k] = __builtin_amdgcn_readlane(MO, k);
      swA[k] = __builtin_amdgcn_readlane(WA, k);
      swB[k] = __builtin_amdgcn_readlane(WB2, k);
    }
    // batch-issue all 9 dwordx4 gathers via asm (compiler cannot serialize)
    f32x4 vv[9];
#pragma unroll
    for (int k = 0; k < 9; ++k) {
      int mk = smo[k];
      int sdx = (mk >> 24) & 1;
      int sdy = ((mk >> 25) & 1) << 7;
      int po = (mk & 0xFFFFFF) + (gxsel ? sdx : 0) + (gysel ? sdy : 0);
      const char* ap = (const char*)xt + ((size_t)(unsigned)po << 8) + lanebyte;
      asm volatile("global_load_dwordx4 %0, %1, off" : "=v"(vv[k]) : "v"(ap));
    }
    asm volatile("s_waitcnt vmcnt(0)");
    __builtin_amdgcn_sched_barrier(0);
    // weighted cross-corner reduce (DPP within quads), group-leader writes LDS
#pragma unroll
    for (int k = 0; k < 9; ++k) {
      int hsel = gysel ? swB[k] : swA[k];
      __half hh = __builtin_bit_cast(__half, (u16)(hsel >> shamt));
      float w = __half2float(hh);
      float r0 = vv[k][0] * w, r1 = vv[k][1] * w, r2 = vv[k][2] * w, r3 = vv[k][3] * w;
      r0 = dpp_add_x2(dpp_add_x1(r0));
      r1 = dpp_add_x2(dpp_add_x1(r1));
      r2 = dpp_add_x2(dpp_add_x1(r2));
      r3 = dpp_add_x2(dpp_add_x1(r3));
      if (corner == 0) {
        ushort4v pk;
        pk.x = __builtin_bit_cast(u16, __float2bfloat16(r0));
        pk.y = __builtin_bit_cast(u16, __float2bfloat16(r1));
        pk.z = __builtin_bit_cast(u16, __float2bfloat16(r2));
        pk.w = __builtin_bit_cast(u16, __float2bfloat16(r3));
        int idx = (p * 576 + k * 64 + (c4 << 2)) ^ ((p & 7) << 3);
        *(ushort4v*)&S[idx] = pk;
      }
    }
  };
#pragma unroll
  for (int i = 0; i < 8; ++i) sample_one(i);

  // A fragments via asm loads (kept out of the sampling vmcnt window)
  s16x8 afr[18];
  const u16* wrow = Wb + (wid * 16 + (lane & 15)) * 576 + (lane >> 4) * 8;
#pragma unroll
  for (int kc = 0; kc < 18; ++kc)
    asm volatile("global_load_dwordx4 %0, %1, off" : "=v"(afr[kc]) : "v"(wrow + kc * 32));

  __syncthreads();
  asm volatile("s_waitcnt vmcnt(0)");
  __builtin_amdgcn_sched_barrier(0);

  f32x4 zero = {0.f, 0.f, 0.f, 0.f};
  f32x4 acc[2] = {zero, zero};
#pragma unroll
  for (int kc = 0; kc < 18; ++kc) {
#pragma unroll
    for (int nf = 0; nf < 2; ++nf) {
      int row = nf * 16 + (lane & 15);
      int idx = (row * 576 + kc * 32 + (lane >> 4) * 8) ^ ((row & 7) << 3);
      bf16x8 bfr = __builtin_bit_cast(bf16x8, *(const s16x8*)&S[idx]);
      acc[nf] = __builtin_amdgcn_mfma_f32_16x16x32_bf16(
          __builtin_bit_cast(bf16x8, afr[kc]), bfr, acc[nf], 0, 0, 0);
    }
  }

  // epilogue: write y (NCHW) only — stats computed by kstats pass
  int obase = wid * 16 + (lane >> 4) * 4;
#pragma unroll
  for (int nf = 0; nf < 2; ++nf) {
    int pix = base + nf * 16 + (lane & 15);
    int hw = pix & 16383;
    float* yp = y + (size_t)b * (64 * HWSZ) + hw;
#pragma unroll
    for (int r = 0; r < 4; ++r) {
      int o = obase + r;
      yp[(size_t)o * HWSZ] = acc[nf][r] + db[o];
    }
  }
}

// ---- BN stats: one block per channel, no atomics ----
__global__ void kstats(const float* __restrict__ y, const float* __restrict__ gamma,
                       const float* __restrict__ beta, float* __restrict__ stats) {
  __shared__ float r1[256], r2[256];
  int o = blockIdx.x;
  int tid = threadIdx.x;
  float s1 = 0.f, s2 = 0.f;
  for (int b = 0; b < 8; ++b) {
    const float* yp = y + (size_t)b * (64 * HWSZ) + (size_t)o * HWSZ;
    for (int i = tid * 4; i < HWSZ; i += 1024) {
      f32x4 v = *(const f32x4*)(yp + i);
#pragma unroll
      for (int j = 0; j < 4; ++j) { s1 += v[j]; s2 += v[j] * v[j]; }
    }
  }
  r1[tid] = s1; r2[tid] = s2;
  __syncthreads();
  for (int s = 128; s > 0; s >>= 1) {
    if (tid < s) { r1[tid] += r1[tid + s]; r2[tid] += r2[tid + s]; }
    __syncthreads();
  }
  if (tid == 0) {
    float m = r1[0] * (1.f / 131072.f);
    float v = r2[0] * (1.f / 131072.f) - m * m;
    float sc = gamma[o] * rsqrtf(v + 1e-5f);
    stats[128 + o] = sc;
    stats[192 + o] = beta[o] - m * sc;
  }
}

// ---- in-place scale/shift + PReLU on y (= d_out) ----
__global__ void kfinal(float* __restrict__ y, const float* __restrict__ stats,
                       const float* __restrict__ pa) {
  float a = pa[0];
  int total = NPIX * 64 / 4;
  for (int i = blockIdx.x * blockDim.x + threadIdx.x; i < total;
       i += gridDim.x * blockDim.x) {
    int o = (i >> 12) & 63;
    f32x4 v = ((const f32x4*)y)[i];
    float sc = stats[128 + o], sh = stats[192 + o];
#pragma unroll
    for (int j = 0; j < 4; ++j) {
      float t = fmaf(v[j], sc, sh);
      v[j] = t >= 0.f ? t : a * t;
    }
    ((f32x4*)y)[i] = v;
  }
}

extern "C" void kernel_launch(void* const* d_in, const int* in_sizes, int n_in,
                              void* d_out, int out_size, void* d_ws, size_t ws_size,
                              hipStream_t stream) {
  const float* x  = (const float*)d_in[0];
  const float* ow = (const float*)d_in[1];
  const float* ob = (const float*)d_in[2];
  const float* dw = (const float*)d_in[3];
  const float* db = (const float*)d_in[4];
  const float* gm = (const float*)d_in[5];
  const float* bt = (const float*)d_in[6];
  const float* pa = (const float*)d_in[7];
  char* ws = (char*)d_ws;
  float* xt    = (float*)(ws + XT_OFF);
  float* offs  = (float*)(ws + OFFS_OFF);
  u16*   Wb    = (u16*)(ws + WB_OFF);
  float* offr  = (float*)(ws + OFFR_OFF);
  float* stats = (float*)(ws + STATS_OFF);
  float* y = (float*)d_out;   // d_out doubles as the pre-BN activation buffer

  kprep<<<185, 256, 0, stream>>>(dw, ow, Wb, offr);
  ktrans<<<2048, 256, 0, stream>>>(x, xt);
  koffc<<<512, 256, 0, stream>>>(xt, offr, ob, offs);
  kdeform<<<4096, 256, 0, stream>>>(xt, offs, Wb, db, y);
  kstats<<<64, 256, 0, stream>>>(y, gm, bt, stats);
  kfinal<<<2048, 256, 0, stream>>>(y, stats, pa);
}